// Round 5
// baseline (1554.715 us; speedup 1.0000x reference)
//
#include <hip/hip_runtime.h>
#include <stdint.h>

#define V_N 25000
#define E_N 50000
#define G_N 1024
#define DIN 74
#define EIN 12
#define NSTEPS 6
#define NS2S 6
#define MPAD 50048   // 782 * 64, padded edge count (zb rows)

typedef unsigned int u32;
typedef unsigned short u16;
typedef __attribute__((ext_vector_type(8))) short bf16x8v;   // 8 bf16 in 4 VGPRs
typedef __attribute__((ext_vector_type(4))) float f32x4v;

__device__ __forceinline__ u16 f2bf(float f) {
  u32 u = __float_as_uint(f);
  u = (u + 0x7fffu + ((u >> 16) & 1u)) >> 16;
  return (u16)u;
}
__device__ __forceinline__ u32 pack2bf(float lo, float hi) {
  return (u32)f2bf(lo) | ((u32)f2bf(hi) << 16);
}
__device__ __forceinline__ float bflo(u32 w){ return __uint_as_float(w << 16); }
__device__ __forceinline__ float bfhi(u32 w){ return __uint_as_float(w & 0xffff0000u); }
__device__ __forceinline__ float sigf(float x){ return 1.f/(1.f + expf(-x)); }
__device__ __forceinline__ float splusf(float x){ return fmaxf(x, 0.f) + log1pf(expf(-fabsf(x))); }

// ---------------- one-time prep: GRU transposes + LSTM bf16-quad packs + W_e2 -> bf16 col-major
// LSTM quad layout: entry q = k8*256 + tt holds uint4; u32 j of it packs W[tt][k8*8+2j], W[tt][k8*8+2j+1]
__global__ void prep_kernel(const float* gWih, const float* gWhh,
                            const float* lWih0, const float* lWhh0,
                            const float* lWihr, const float* lWhhr,
                            const float* We2,
                            float* gWihT, float* gWhhT,
                            u32* TW40, u32* TU40, u32* TW4r, u32* TU4r,
                            u16* WbT) {
  int idx = blockIdx.x * 256 + threadIdx.x;
  if (idx < 12288) { int d = idx / 192, r = idx % 192; gWihT[idx] = gWih[r*64 + d]; return; }
  idx -= 12288;
  if (idx < 12288) { int d = idx / 192, r = idx % 192; gWhhT[idx] = gWhh[r*64 + d]; return; }
  idx -= 12288;
  if (idx < 16384) { int q = idx >> 2, j = idx & 3; int k8 = q >> 8, r = q & 255;
                     TW40[idx] = pack2bf(lWih0[r*128 + k8*8 + 2*j], lWih0[r*128 + k8*8 + 2*j + 1]); return; }
  idx -= 16384;
  if (idx < 8192)  { int q = idx >> 2, j = idx & 3; int k8 = q >> 8, r = q & 255;
                     TU40[idx] = pack2bf(lWhh0[r*64 + k8*8 + 2*j], lWhh0[r*64 + k8*8 + 2*j + 1]); return; }
  idx -= 8192;
  if (idx < 16384) { int l = idx >> 13, rem = idx & 8191; int q = rem >> 2, j = rem & 3;
                     int k8 = q >> 8, r = q & 255;
                     TW4r[idx] = pack2bf(lWihr[l*16384 + r*64 + k8*8 + 2*j],
                                         lWihr[l*16384 + r*64 + k8*8 + 2*j + 1]); return; }
  idx -= 16384;
  if (idx < 16384) { int l = idx >> 13, rem = idx & 8191; int q = rem >> 2, j = rem & 3;
                     int k8 = q >> 8, r = q & 255;
                     TU4r[idx] = pack2bf(lWhhr[l*16384 + r*64 + k8*8 + 2*j],
                                         lWhhr[l*16384 + r*64 + k8*8 + 2*j + 1]); return; }
  idx -= 16384;
  { int n = idx / 128, k = idx % 128; WbT[idx] = f2bf(We2[k*4096 + n]); }
}

// ---------------- h0 = relu(node_feats @ W_proj + b_proj), wave per node
__global__ void proj_kernel(const float* nf, const float* Wp, const float* bp, float* h) {
  int v = blockIdx.x * 4 + (threadIdx.x >> 6);
  int o = threadIdx.x & 63;
  if (v >= V_N) return;
  float acc = bp[o];
  const float* row = nf + (size_t)v * DIN;
  #pragma unroll 2
  for (int d = 0; d < DIN; ++d) acc += row[d] * Wp[d*64 + o];
  h[(size_t)v*64 + o] = fmaxf(acc, 0.f);
}

// ---------------- z = relu(edge_feats @ W_e1 + b_e1) -> bf16, padded rows get 0
__global__ void edgenet_kernel(const float* ef, const float* W1, const float* b1, u16* zb) {
  int e = blockIdx.x * 2 + (threadIdx.x >> 7);
  int k = threadIdx.x & 127;
  float acc = 0.f;
  if (e < E_N) {
    acc = b1[k];
    const float* row = ef + (size_t)e * EIN;
    #pragma unroll
    for (int i = 0; i < EIN; ++i) acc += row[i] * W1[i*128 + k];
    acc = fmaxf(acc, 0.f);
  }
  zb[(size_t)e*128 + k] = f2bf(acc);
}

// ---------------- fused per-step message kernel v3: 1 wave per block, 64 edges, register GEMM.
// A (z rows) in 64 VGPRs for the whole kernel; B frags streamed from L2 per d-slice;
// C = z@W_e2[:,d*64:+64] + b_e2 via MFMA; m += h[src][d] * C folded per d; atomic scatter at end.
// No LDS staging of A/B, no barriers in the main loop.
__global__ __launch_bounds__(64) void fusedmsg_kernel(const u16* zb, const u16* WbT, const float* be2,
                                                      const float* h, const int* src, const int* dst,
                                                      float* agg) {
  __shared__ float hS[64][65];                 // +1 pad: fold reads 4 rows/group, breaks bank alias
  int lane = threadIdx.x;
  int e0 = blockIdx.x * 64;
  int l16 = lane & 15, lh = lane >> 4;

  // coalesced gather of h[src[e]] rows (src[e0+row] is wave-uniform -> scalar load)
  for (int row = 0; row < 64; ++row) {
    int e = e0 + row;
    int sv = (e < E_N) ? src[e] : 0;
    hS[row][lane] = h[(size_t)sv * 64 + lane];
  }

  // A fragments: af[rf][ks], lane holds zb[e0 + rf*16 + l16][ks*32 + lh*8 .. +8)
  bf16x8v af[4][4];
  #pragma unroll
  for (int rf = 0; rf < 4; ++rf)
    #pragma unroll
    for (int ks = 0; ks < 4; ++ks)
      af[rf][ks] = *(const bf16x8v*)(zb + (size_t)(e0 + rf*16 + l16)*128 + ks*32 + lh*8);

  f32x4v m[4][4];                              // [rf][of]; rows rf*16+lh*4+r, cols of*16+l16
  #pragma unroll
  for (int rf = 0; rf < 4; ++rf)
    #pragma unroll
    for (int of = 0; of < 4; ++of)
      #pragma unroll
      for (int r = 0; r < 4; ++r) m[rf][of][r] = 0.f;

  #pragma unroll 2
  for (int d = 0; d < 64; ++d) {
    float hv[4][4];
    #pragma unroll
    for (int rf = 0; rf < 4; ++rf)
      #pragma unroll
      for (int r = 0; r < 4; ++r)
        hv[rf][r] = hS[rf*16 + lh*4 + r][d];

    #pragma unroll
    for (int of = 0; of < 4; ++of) {
      const u16* Bb = WbT + (size_t)(d*64 + of*16 + l16)*128 + lh*8;
      bf16x8v b0 = *(const bf16x8v*)(Bb);
      bf16x8v b1 = *(const bf16x8v*)(Bb + 32);
      bf16x8v b2 = *(const bf16x8v*)(Bb + 64);
      bf16x8v b3 = *(const bf16x8v*)(Bb + 96);
      float bias = be2[d*64 + of*16 + l16];
      f32x4v c[4];
      #pragma unroll
      for (int rf = 0; rf < 4; ++rf) c[rf] = (f32x4v){bias, bias, bias, bias};
      #pragma unroll
      for (int rf = 0; rf < 4; ++rf) {
        c[rf] = __builtin_amdgcn_mfma_f32_16x16x32_bf16(af[rf][0], b0, c[rf], 0, 0, 0);
        c[rf] = __builtin_amdgcn_mfma_f32_16x16x32_bf16(af[rf][1], b1, c[rf], 0, 0, 0);
        c[rf] = __builtin_amdgcn_mfma_f32_16x16x32_bf16(af[rf][2], b2, c[rf], 0, 0, 0);
        c[rf] = __builtin_amdgcn_mfma_f32_16x16x32_bf16(af[rf][3], b3, c[rf], 0, 0, 0);
      }
      #pragma unroll
      for (int rf = 0; rf < 4; ++rf)
        #pragma unroll
        for (int r = 0; r < 4; ++r)
          m[rf][of][r] += hv[rf][r] * c[rf][r];
    }
  }

  // scatter messages
  #pragma unroll
  for (int rf = 0; rf < 4; ++rf)
    #pragma unroll
    for (int r = 0; r < 4; ++r) {
      int row = rf*16 + lh*4 + r;
      int e = e0 + row;
      if (e < E_N) {
        int dv = dst[e];
        #pragma unroll
        for (int of = 0; of < 4; ++of)
          atomicAdd(&agg[(size_t)dv*64 + of*16 + l16], m[rf][of][r]);
      }
    }
}

// ---------------- GRU: h = GRU(relu(agg + b_conv), h); wave handles 4 nodes; zeroes agg after read
__global__ void gru_kernel(const float* aggc, const float* bconv, const float* WihT, const float* WhhT,
                           const float* bih, const float* bhh, float* h, float* aggz) {
  int wbase = (blockIdx.x * 4 + (threadIdx.x >> 6)) * 4;
  int o = threadIdx.x & 63;
  float xv[4], hv[4];
  #pragma unroll
  for (int n = 0; n < 4; ++n) {
    int v = wbase + n;
    if (v < V_N) { xv[n] = fmaxf(aggc[(size_t)v*64 + o] + bconv[o], 0.f); hv[n] = h[(size_t)v*64 + o]; }
    else { xv[n] = 0.f; hv[n] = 0.f; }
  }
  float ar[4] = {0,0,0,0}, az[4] = {0,0,0,0}, an[4] = {0,0,0,0};
  float br[4] = {0,0,0,0}, bz[4] = {0,0,0,0}, bn2[4] = {0,0,0,0};
  #pragma unroll 4
  for (int d = 0; d < 64; ++d) {
    float wr = WihT[d*192 + o], wz = WihT[d*192 + 64 + o], wn = WihT[d*192 + 128 + o];
    float ur = WhhT[d*192 + o], uz = WhhT[d*192 + 64 + o], un = WhhT[d*192 + 128 + o];
    #pragma unroll
    for (int n = 0; n < 4; ++n) {
      float xd = __shfl(xv[n], d);
      float hd = __shfl(hv[n], d);
      ar[n] += xd*wr; az[n] += xd*wz; an[n] += xd*wn;
      br[n] += hd*ur; bz[n] += hd*uz; bn2[n] += hd*un;
    }
  }
  float b_r = bih[o] + bhh[o], b_z = bih[64+o] + bhh[64+o];
  float bin = bih[128+o], bhn = bhh[128+o];
  #pragma unroll
  for (int n = 0; n < 4; ++n) {
    int v = wbase + n;
    if (v >= V_N) continue;
    float r  = sigf(ar[n] + br[n] + b_r);
    float z  = sigf(az[n] + bz[n] + b_z);
    float nn = tanhf(an[n] + bin + r*(bn2[n] + bhn));
    h[(size_t)v*64 + o] = (1.f - z)*nn + z*hv[n];
    aggz[(size_t)v*64 + o] = 0.f;              // re-zero for next msg step
  }
}

// ---------------- graph segment starts via binary search (node2graph is sorted)
__global__ void gstart_kernel(const int* n2g, int* gstart) {
  int g = blockIdx.x * 256 + threadIdx.x;
  if (g > G_N) return;
  int lo = 0, hi = V_N;
  while (lo < hi) { int mid = (lo + hi) >> 1; if (n2g[mid] < g) lo = mid + 1; else hi = mid; }
  gstart[g] = lo;
}

// ---------------- fused Set2Set v3: 4 graphs per 256-thread block; LSTM weights as bf16 uint4 quads
__global__ __launch_bounds__(256) void s2s_kernel(const float* h, const int* gstart,
    const uint4* TW40, const uint4* TU40, const uint4* TW4r, const uint4* TU4r,
    const float* bih0, const float* bhh0, const float* bihr, const float* bhhr,
    float* qstar) {
  __shared__ float sq[4][128];
  __shared__ float sx[4][128];
  __shared__ float shs[4][3][64], scs[4][3][64];
  __shared__ float sg[4][256];
  int tt = threadIdx.x;
  int g0blk = blockIdx.x * 4;
  int w = tt >> 6, lane = tt & 63;
  int nstart = gstart[g0blk + w], nend = gstart[g0blk + w + 1];

  for (int i = tt; i < 512; i += 256) ((float*)sq)[i] = 0.f;
  for (int i = tt; i < 768; i += 256) { ((float*)shs)[i] = 0.f; ((float*)scs)[i] = 0.f; }
  __syncthreads();

  for (int iter = 0; iter < NS2S; ++iter) {
    for (int i = tt; i < 512; i += 256) ((float*)sx)[i] = ((float*)sq)[i];
    __syncthreads();

    for (int l = 0; l < 3; ++l) {
      const uint4* TW = (l == 0) ? TW40 : TW4r + (size_t)(l-1) * 2048;
      const uint4* TU = (l == 0) ? TU40 : TU4r + (size_t)(l-1) * 2048;
      const float* bi = (l == 0) ? bih0 : bihr + (l-1)*256;
      const float* bh = (l == 0) ? bhh0 : bhhr + (l-1)*256;
      float bsum = bi[tt] + bh[tt];
      float acc[4] = {bsum, bsum, bsum, bsum};
      if (l == 0) {
        #pragma unroll
        for (int k8 = 0; k8 < 16; ++k8) {
          uint4 u = TW[k8*256 + tt];
          #pragma unroll
          for (int gi = 0; gi < 4; ++gi) {
            const float4 xa = *(const float4*)&sx[gi][k8*8];
            const float4 xb = *(const float4*)&sx[gi][k8*8 + 4];
            acc[gi] += xa.x*bflo(u.x) + xa.y*bfhi(u.x) + xa.z*bflo(u.y) + xa.w*bfhi(u.y)
                     + xb.x*bflo(u.z) + xb.y*bfhi(u.z) + xb.z*bflo(u.w) + xb.w*bfhi(u.w);
          }
        }
      } else {
        #pragma unroll
        for (int k8 = 0; k8 < 8; ++k8) {
          uint4 u = TW[k8*256 + tt];
          #pragma unroll
          for (int gi = 0; gi < 4; ++gi) {
            const float4 xa = *(const float4*)&sx[gi][k8*8];
            const float4 xb = *(const float4*)&sx[gi][k8*8 + 4];
            acc[gi] += xa.x*bflo(u.x) + xa.y*bfhi(u.x) + xa.z*bflo(u.y) + xa.w*bfhi(u.y)
                     + xb.x*bflo(u.z) + xb.y*bfhi(u.z) + xb.z*bflo(u.w) + xb.w*bfhi(u.w);
          }
        }
      }
      #pragma unroll
      for (int k8 = 0; k8 < 8; ++k8) {
        uint4 u = TU[k8*256 + tt];
        #pragma unroll
        for (int gi = 0; gi < 4; ++gi) {
          const float4 ha = *(const float4*)&shs[gi][l][k8*8];
          const float4 hb = *(const float4*)&shs[gi][l][k8*8 + 4];
          acc[gi] += ha.x*bflo(u.x) + ha.y*bfhi(u.x) + ha.z*bflo(u.y) + ha.w*bfhi(u.y)
                   + hb.x*bflo(u.z) + hb.y*bfhi(u.z) + hb.z*bflo(u.w) + hb.w*bfhi(u.w);
        }
      }
      #pragma unroll
      for (int gi = 0; gi < 4; ++gi) sg[gi][tt] = acc[gi];
      __syncthreads();
      {
        int gq = tt >> 6, r = tt & 63;
        float gv_i = sg[gq][r], gv_f = sg[gq][64+r], gv_g = sg[gq][128+r], gv_o = sg[gq][192+r];
        float c = sigf(gv_f)*scs[gq][l][r] + sigf(gv_i)*tanhf(gv_g);
        float hc = sigf(gv_o)*tanhf(c);
        scs[gq][l][r] = c; shs[gq][l][r] = hc; sx[gq][r] = hc;
      }
      __syncthreads();
    }

    // attention: wave w owns graph g0blk+w; q = sx[w][0:64]
    {
      float q_l = sx[w][lane];
      float lmax = -3.4e38f;
      int i = nstart;
      for (; i + 1 < nend; i += 2) {
        float h0 = h[(size_t)i*64 + lane];
        float h1 = h[(size_t)(i+1)*64 + lane];
        float v0 = h0 * q_l, v1 = h1 * q_l;
        #pragma unroll
        for (int off = 32; off; off >>= 1) { v0 += __shfl_xor(v0, off); v1 += __shfl_xor(v1, off); }
        lmax = fmaxf(lmax, fmaxf(v0, v1));
      }
      if (i < nend) {
        float h0 = h[(size_t)i*64 + lane];
        float v0 = h0 * q_l;
        #pragma unroll
        for (int off = 32; off; off >>= 1) v0 += __shfl_xor(v0, off);
        lmax = fmaxf(lmax, v0);
      }
      float lsum = 0.f, accv = 0.f;
      i = nstart;
      for (; i + 1 < nend; i += 2) {
        float h0 = h[(size_t)i*64 + lane];
        float h1 = h[(size_t)(i+1)*64 + lane];
        float v0 = h0 * q_l, v1 = h1 * q_l;
        #pragma unroll
        for (int off = 32; off; off >>= 1) { v0 += __shfl_xor(v0, off); v1 += __shfl_xor(v1, off); }
        float e0 = expf(v0 - lmax), e1 = expf(v1 - lmax);
        lsum += e0 + e1; accv += e0*h0 + e1*h1;
      }
      if (i < nend) {
        float h0 = h[(size_t)i*64 + lane];
        float v0 = h0 * q_l;
        #pragma unroll
        for (int off = 32; off; off >>= 1) v0 += __shfl_xor(v0, off);
        float e0 = expf(v0 - lmax);
        lsum += e0; accv += e0*h0;
      }
      sq[w][lane] = sx[w][lane];
      sq[w][64 + lane] = accv / fmaxf(lsum, 1e-12f);
    }
    __syncthreads();
  }

  for (int i = tt; i < 512; i += 256) qstar[(size_t)g0blk * 128 + i] = ((float*)sq)[i];
}

// ---------------- head: Linear+ReLU+BN(eval)+Linear + evidential transform; wave per graph
__global__ void head_kernel(const float* qstar, const float* W1, const float* b1,
                            const float* gma, const float* gbe, const float* gme, const float* gva,
                            const float* W2, const float* b2, float* out) {
  __shared__ float hb[4][64];
  int wslot = threadIdx.x >> 6;
  int g = blockIdx.x * 4 + wslot;
  int o = threadIdx.x & 63;
  float acc = b1[o];
  const float* q = qstar + (size_t)g * 128;
  #pragma unroll 4
  for (int k = 0; k < 128; ++k) acc += q[k] * W1[k*64 + o];
  acc = fmaxf(acc, 0.f);
  float hbn = gma[o] * (acc - gme[o]) * rsqrtf(gva[o] + 1e-5f) + gbe[o];
  hb[wslot][o] = hbn;
  __syncthreads();
  if (o < 4) {
    float v = b2[o];
    #pragma unroll 8
    for (int k = 0; k < 64; ++k) v += hb[wslot][k] * W2[k*4 + o];
    float res;
    if (o == 0) res = v;
    else { res = splusf(v) + 1e-6f; if (o == 2) res += 1.f; }
    out[(size_t)g*4 + o] = res;
  }
}

extern "C" void kernel_launch(void* const* d_in, const int* in_sizes, int n_in,
                              void* d_out, int out_size, void* d_ws, size_t ws_size,
                              hipStream_t stream) {
  const float* node_feats = (const float*)d_in[0];
  const float* edge_feats = (const float*)d_in[1];
  const int*   src        = (const int*)d_in[2];
  const int*   dst        = (const int*)d_in[3];
  const int*   n2g        = (const int*)d_in[4];
  const float* W_proj = (const float*)d_in[5];
  const float* b_proj = (const float*)d_in[6];
  const float* W_e1   = (const float*)d_in[7];
  const float* b_e1   = (const float*)d_in[8];
  const float* W_e2   = (const float*)d_in[9];
  const float* b_e2   = (const float*)d_in[10];
  const float* b_conv = (const float*)d_in[11];
  const float* gru_W_ih = (const float*)d_in[12];
  const float* gru_W_hh = (const float*)d_in[13];
  const float* gru_b_ih = (const float*)d_in[14];
  const float* gru_b_hh = (const float*)d_in[15];
  const float* lstm_W_ih0 = (const float*)d_in[16];
  const float* lstm_W_hh0 = (const float*)d_in[17];
  const float* lstm_b_ih0 = (const float*)d_in[18];
  const float* lstm_b_hh0 = (const float*)d_in[19];
  const float* lstm_W_ih_r = (const float*)d_in[20];
  const float* lstm_W_hh_r = (const float*)d_in[21];
  const float* lstm_b_ih_r = (const float*)d_in[22];
  const float* lstm_b_hh_r = (const float*)d_in[23];
  const float* W1 = (const float*)d_in[24];
  const float* b1 = (const float*)d_in[25];
  const float* bn_gamma = (const float*)d_in[26];
  const float* bn_beta  = (const float*)d_in[27];
  const float* bn_mean  = (const float*)d_in[28];
  const float* bn_var   = (const float*)d_in[29];
  const float* W2 = (const float*)d_in[30];
  const float* b2 = (const float*)d_in[31];

  char* ws = (char*)d_ws;
  size_t off = 0;
  auto alloc = [&](size_t n) { size_t c = off; off += (n + 255) & ~(size_t)255; return c; };
  u16*   zb     = (u16*)  (ws + alloc((size_t)MPAD * 128 * 2));   // 12.8 MB
  float* h      = (float*)(ws + alloc((size_t)V_N * 64 * 4));     //  6.4 MB
  float* agg    = (float*)(ws + alloc((size_t)V_N * 64 * 4));     //  6.4 MB
  u16*   WbT    = (u16*)  (ws + alloc((size_t)4096 * 128 * 2));   //  1.0 MB
  float* gWihT  = (float*)(ws + alloc(12288 * 4));
  float* gWhhT  = (float*)(ws + alloc(12288 * 4));
  u32*   TW40   = (u32*)  (ws + alloc(16384 * 4));
  u32*   TU40   = (u32*)  (ws + alloc(8192 * 4));
  u32*   TW4r   = (u32*)  (ws + alloc(16384 * 4));
  u32*   TU4r   = (u32*)  (ws + alloc(16384 * 4));
  int*   gstart = (int*)  (ws + alloc(1025 * 4));
  float* qstar  = (float*)(ws + alloc((size_t)G_N * 128 * 4));
  (void)in_sizes; (void)n_in; (void)out_size; (void)ws_size;

  prep_kernel<<<2368, 256, 0, stream>>>(gru_W_ih, gru_W_hh, lstm_W_ih0, lstm_W_hh0,
                                        lstm_W_ih_r, lstm_W_hh_r, W_e2,
                                        gWihT, gWhhT, TW40, TU40, TW4r, TU4r, WbT);
  proj_kernel<<<6250, 256, 0, stream>>>(node_feats, W_proj, b_proj, h);
  edgenet_kernel<<<MPAD / 2, 256, 0, stream>>>(edge_feats, W_e1, b_e1, zb);
  hipMemsetAsync(agg, 0, (size_t)V_N * 64 * 4, stream);

  for (int st = 0; st < NSTEPS; ++st) {
    fusedmsg_kernel<<<MPAD / 64, 64, 0, stream>>>(zb, WbT, b_e2, h, src, dst, agg);
    gru_kernel<<<1563, 256, 0, stream>>>(agg, b_conv, gWihT, gWhhT, gru_b_ih, gru_b_hh, h, agg);
  }

  gstart_kernel<<<5, 256, 0, stream>>>(n2g, gstart);
  s2s_kernel<<<256, 256, 0, stream>>>(h, gstart, (const uint4*)TW40, (const uint4*)TU40,
                                      (const uint4*)TW4r, (const uint4*)TU4r,
                                      lstm_b_ih0, lstm_b_hh0, lstm_b_ih_r, lstm_b_hh_r, qstar);
  head_kernel<<<256, 256, 0, stream>>>(qstar, W1, b1, bn_gamma, bn_beta, bn_mean, bn_var,
                                       W2, b2, (float*)d_out);
}

// Round 6
// 1080.882 us; speedup vs baseline: 1.4384x; 1.4384x over previous
//
#include <hip/hip_runtime.h>
#include <stdint.h>

#define V_N 25000
#define E_N 50000
#define G_N 1024
#define DIN 74
#define EIN 12
#define NSTEPS 6
#define NS2S 6
#define MPAD 50048   // 391 * 128, padded edge count (zb rows)

typedef unsigned int u32;
typedef unsigned short u16;
typedef __attribute__((ext_vector_type(8))) short bf16x8v;   // 8 bf16 in 4 VGPRs
typedef __attribute__((ext_vector_type(4))) float f32x4v;

typedef __attribute__((address_space(3))) void lds_void;
typedef __attribute__((address_space(1))) void gbl_void;

__device__ __forceinline__ void gload_lds16(const void* g, void* l) {
  __builtin_amdgcn_global_load_lds((gbl_void*)g, (lds_void*)l, 16, 0, 0);
}

__device__ __forceinline__ u16 f2bf(float f) {
  u32 u = __float_as_uint(f);
  u = (u + 0x7fffu + ((u >> 16) & 1u)) >> 16;
  return (u16)u;
}
__device__ __forceinline__ u32 pack2bf(float lo, float hi) {
  return (u32)f2bf(lo) | ((u32)f2bf(hi) << 16);
}
__device__ __forceinline__ float bflo(u32 w){ return __uint_as_float(w << 16); }
__device__ __forceinline__ float bfhi(u32 w){ return __uint_as_float(w & 0xffff0000u); }
__device__ __forceinline__ float sigf(float x){ return 1.f/(1.f + expf(-x)); }
__device__ __forceinline__ float splusf(float x){ return fmaxf(x, 0.f) + log1pf(expf(-fabsf(x))); }

// ---------------- one-time prep: GRU transposes + LSTM bf16-quad packs + W_e2 -> bf16 col-major
// LSTM quad layout: entry q = k8*256 + tt holds uint4; u32 j of it packs W[tt][k8*8+2j], W[tt][k8*8+2j+1]
__global__ void prep_kernel(const float* gWih, const float* gWhh,
                            const float* lWih0, const float* lWhh0,
                            const float* lWihr, const float* lWhhr,
                            const float* We2,
                            float* gWihT, float* gWhhT,
                            u32* TW40, u32* TU40, u32* TW4r, u32* TU4r,
                            u16* WbT) {
  int idx = blockIdx.x * 256 + threadIdx.x;
  if (idx < 12288) { int d = idx / 192, r = idx % 192; gWihT[idx] = gWih[r*64 + d]; return; }
  idx -= 12288;
  if (idx < 12288) { int d = idx / 192, r = idx % 192; gWhhT[idx] = gWhh[r*64 + d]; return; }
  idx -= 12288;
  if (idx < 16384) { int q = idx >> 2, j = idx & 3; int k8 = q >> 8, r = q & 255;
                     TW40[idx] = pack2bf(lWih0[r*128 + k8*8 + 2*j], lWih0[r*128 + k8*8 + 2*j + 1]); return; }
  idx -= 16384;
  if (idx < 8192)  { int q = idx >> 2, j = idx & 3; int k8 = q >> 8, r = q & 255;
                     TU40[idx] = pack2bf(lWhh0[r*64 + k8*8 + 2*j], lWhh0[r*64 + k8*8 + 2*j + 1]); return; }
  idx -= 8192;
  if (idx < 16384) { int l = idx >> 13, rem = idx & 8191; int q = rem >> 2, j = rem & 3;
                     int k8 = q >> 8, r = q & 255;
                     TW4r[idx] = pack2bf(lWihr[l*16384 + r*64 + k8*8 + 2*j],
                                         lWihr[l*16384 + r*64 + k8*8 + 2*j + 1]); return; }
  idx -= 16384;
  if (idx < 16384) { int l = idx >> 13, rem = idx & 8191; int q = rem >> 2, j = rem & 3;
                     int k8 = q >> 8, r = q & 255;
                     TU4r[idx] = pack2bf(lWhhr[l*16384 + r*64 + k8*8 + 2*j],
                                         lWhhr[l*16384 + r*64 + k8*8 + 2*j + 1]); return; }
  idx -= 16384;
  { int n = idx / 128, k = idx % 128; WbT[idx] = f2bf(We2[k*4096 + n]); }
}

// ---------------- h0 = relu(node_feats @ W_proj + b_proj), wave per node
__global__ void proj_kernel(const float* nf, const float* Wp, const float* bp, float* h) {
  int v = blockIdx.x * 4 + (threadIdx.x >> 6);
  int o = threadIdx.x & 63;
  if (v >= V_N) return;
  float acc = bp[o];
  const float* row = nf + (size_t)v * DIN;
  #pragma unroll 2
  for (int d = 0; d < DIN; ++d) acc += row[d] * Wp[d*64 + o];
  h[(size_t)v*64 + o] = fmaxf(acc, 0.f);
}

// ---------------- z = relu(edge_feats @ W_e1 + b_e1) -> bf16, padded rows get 0
__global__ void edgenet_kernel(const float* ef, const float* W1, const float* b1, u16* zb) {
  int e = blockIdx.x * 2 + (threadIdx.x >> 7);
  int k = threadIdx.x & 127;
  float acc = 0.f;
  if (e < E_N) {
    acc = b1[k];
    const float* row = ef + (size_t)e * EIN;
    #pragma unroll
    for (int i = 0; i < EIN; ++i) acc += row[i] * W1[i*128 + k];
    acc = fmaxf(acc, 0.f);
  }
  zb[(size_t)e*128 + k] = f2bf(acc);
}

// ---------------- fused per-step message kernel v4:
// Block = 128 edges, 512 threads = 8 waves; wave w owns edge-rows w*16..+16 with A (z) in REGISTERS.
// B streamed through LDS in 64-col tiles (one d per tile), double-buffered, XOR-swizzled.
// LDS = 2x16KB (B) + 33.8KB (hS) = 66KB -> 2 blocks/CU co-resident.
// Per tile: wave computes full 16x64 C sub-tile (4 of x 4 ks MFMA) + scalar-h fold. No merge pass.
__global__ __launch_bounds__(512) void fusedmsg_kernel(const u16* zb, const u16* WbT, const float* be2,
                                                       const float* h, const int* src, const int* dst,
                                                       float* agg) {
  __shared__ __align__(16) u16 Bs[2][8192];    // 64 cols x 128 k, double-buffered
  __shared__ float hS[128][66];                // gathered h[src[e]] rows (+2 pad)
  int t = threadIdx.x;
  int e0 = blockIdx.x * 128;
  int w = t >> 6, lane = t & 63;
  int l16 = lane & 15, lh = lane >> 4;

  // gather h rows for this block's edges (coalesced 256B per edge row)
  for (int it = 0; it < 16; ++it) {
    int idx = it * 512 + t;
    int el = idx >> 6, d = idx & 63;
    int e = e0 + el;
    int sv = (e < E_N) ? src[e] : 0;
    hS[el][d] = h[(size_t)sv * 64 + d];
  }

  // A fragments in registers: wave w rows w*16..+16; af[ks] lane holds zb[row][ks*32+lh*8 ..+8)
  bf16x8v af[4];
  #pragma unroll
  for (int ks = 0; ks < 4; ++ks)
    af[ks] = *(const bf16x8v*)(zb + (size_t)(e0 + w*16 + l16)*128 + ks*32 + lh*8);

  // stage B tile 0 (1024 chunks of 16B, 2 per thread), XOR-swizzled: LDS[r][s] = glob[r][s^(r&7)]
  {
    const char* Bg = (const char*)WbT;
    char* Bl = (char*)Bs[0];
    #pragma unroll
    for (int it = 0; it < 2; ++it) {
      int f = it * 512 + t;
      int r = f >> 4, s = f & 15;
      int gc = s ^ (r & 7);
      gload_lds16(Bg + r*256 + gc*16, Bl + (size_t)(f & ~63) * 16);
    }
  }
  __syncthreads();

  float macc[4][4];                            // [of][r]: col of*16+l16, row w*16+lh*4+r
  #pragma unroll
  for (int of = 0; of < 4; ++of)
    #pragma unroll
    for (int r = 0; r < 4; ++r) macc[of][r] = 0.f;

  for (int d = 0; d < 64; ++d) {
    int buf = d & 1;
    if (d < 63) {                              // prefetch next 64-col tile
      const char* Bg = (const char*)WbT + (size_t)(d + 1) * 16384;
      char* Bl = (char*)Bs[buf ^ 1];
      #pragma unroll
      for (int it = 0; it < 2; ++it) {
        int f = it * 512 + t;
        int r = f >> 4, s = f & 15;
        int gc = s ^ (r & 7);
        gload_lds16(Bg + r*256 + gc*16, Bl + (size_t)(f & ~63) * 16);
      }
    }
    float hv[4];
    #pragma unroll
    for (int r = 0; r < 4; ++r) hv[r] = hS[w*16 + lh*4 + r][d];

    const char* Bb = (const char*)Bs[buf];
    #pragma unroll
    for (int of = 0; of < 4; ++of) {
      float bias = be2[d*64 + of*16 + l16];
      f32x4v c = (f32x4v){bias, bias, bias, bias};
      #pragma unroll
      for (int ks = 0; ks < 4; ++ks) {
        int brow = of*16 + l16;
        int cb = ks*4 + lh;
        bf16x8v bf = *(const bf16x8v*)(Bb + brow*256 + ((cb ^ (brow & 7)) << 4));
        c = __builtin_amdgcn_mfma_f32_16x16x32_bf16(af[ks], bf, c, 0, 0, 0);
      }
      #pragma unroll
      for (int r = 0; r < 4; ++r) macc[of][r] += hv[r] * c[r];
    }
    __syncthreads();                           // readers done with Bs[buf] + prefetch drained
  }

  // scatter messages
  #pragma unroll
  for (int r = 0; r < 4; ++r) {
    int row = w*16 + lh*4 + r;
    int e = e0 + row;
    if (e < E_N) {
      int dv = dst[e];
      #pragma unroll
      for (int of = 0; of < 4; ++of)
        atomicAdd(&agg[(size_t)dv*64 + of*16 + l16], macc[of][r]);
    }
  }
}

// ---------------- GRU: h = GRU(relu(agg + b_conv), h); wave handles 4 nodes; zeroes agg after read
__global__ void gru_kernel(const float* aggc, const float* bconv, const float* WihT, const float* WhhT,
                           const float* bih, const float* bhh, float* h, float* aggz) {
  int wbase = (blockIdx.x * 4 + (threadIdx.x >> 6)) * 4;
  int o = threadIdx.x & 63;
  float xv[4], hv[4];
  #pragma unroll
  for (int n = 0; n < 4; ++n) {
    int v = wbase + n;
    if (v < V_N) { xv[n] = fmaxf(aggc[(size_t)v*64 + o] + bconv[o], 0.f); hv[n] = h[(size_t)v*64 + o]; }
    else { xv[n] = 0.f; hv[n] = 0.f; }
  }
  float ar[4] = {0,0,0,0}, az[4] = {0,0,0,0}, an[4] = {0,0,0,0};
  float br[4] = {0,0,0,0}, bz[4] = {0,0,0,0}, bn2[4] = {0,0,0,0};
  #pragma unroll 4
  for (int d = 0; d < 64; ++d) {
    float wr = WihT[d*192 + o], wz = WihT[d*192 + 64 + o], wn = WihT[d*192 + 128 + o];
    float ur = WhhT[d*192 + o], uz = WhhT[d*192 + 64 + o], un = WhhT[d*192 + 128 + o];
    #pragma unroll
    for (int n = 0; n < 4; ++n) {
      float xd = __shfl(xv[n], d);
      float hd = __shfl(hv[n], d);
      ar[n] += xd*wr; az[n] += xd*wz; an[n] += xd*wn;
      br[n] += hd*ur; bz[n] += hd*uz; bn2[n] += hd*un;
    }
  }
  float b_r = bih[o] + bhh[o], b_z = bih[64+o] + bhh[64+o];
  float bin = bih[128+o], bhn = bhh[128+o];
  #pragma unroll
  for (int n = 0; n < 4; ++n) {
    int v = wbase + n;
    if (v >= V_N) continue;
    float r  = sigf(ar[n] + br[n] + b_r);
    float z  = sigf(az[n] + bz[n] + b_z);
    float nn = tanhf(an[n] + bin + r*(bn2[n] + bhn));
    h[(size_t)v*64 + o] = (1.f - z)*nn + z*hv[n];
    aggz[(size_t)v*64 + o] = 0.f;              // re-zero for next msg step
  }
}

// ---------------- graph segment starts via binary search (node2graph is sorted)
__global__ void gstart_kernel(const int* n2g, int* gstart) {
  int g = blockIdx.x * 256 + threadIdx.x;
  if (g > G_N) return;
  int lo = 0, hi = V_N;
  while (lo < hi) { int mid = (lo + hi) >> 1; if (n2g[mid] < g) lo = mid + 1; else hi = mid; }
  gstart[g] = lo;
}

// ---------------- fused Set2Set v3: 4 graphs per 256-thread block; LSTM weights as bf16 uint4 quads
__global__ __launch_bounds__(256) void s2s_kernel(const float* h, const int* gstart,
    const uint4* TW40, const uint4* TU40, const uint4* TW4r, const uint4* TU4r,
    const float* bih0, const float* bhh0, const float* bihr, const float* bhhr,
    float* qstar) {
  __shared__ float sq[4][128];
  __shared__ float sx[4][128];
  __shared__ float shs[4][3][64], scs[4][3][64];
  __shared__ float sg[4][256];
  int tt = threadIdx.x;
  int g0blk = blockIdx.x * 4;
  int w = tt >> 6, lane = tt & 63;
  int nstart = gstart[g0blk + w], nend = gstart[g0blk + w + 1];

  for (int i = tt; i < 512; i += 256) ((float*)sq)[i] = 0.f;
  for (int i = tt; i < 768; i += 256) { ((float*)shs)[i] = 0.f; ((float*)scs)[i] = 0.f; }
  __syncthreads();

  for (int iter = 0; iter < NS2S; ++iter) {
    for (int i = tt; i < 512; i += 256) ((float*)sx)[i] = ((float*)sq)[i];
    __syncthreads();

    for (int l = 0; l < 3; ++l) {
      const uint4* TW = (l == 0) ? TW40 : TW4r + (size_t)(l-1) * 2048;
      const uint4* TU = (l == 0) ? TU40 : TU4r + (size_t)(l-1) * 2048;
      const float* bi = (l == 0) ? bih0 : bihr + (l-1)*256;
      const float* bh = (l == 0) ? bhh0 : bhhr + (l-1)*256;
      float bsum = bi[tt] + bh[tt];
      float acc[4] = {bsum, bsum, bsum, bsum};
      if (l == 0) {
        #pragma unroll
        for (int k8 = 0; k8 < 16; ++k8) {
          uint4 u = TW[k8*256 + tt];
          #pragma unroll
          for (int gi = 0; gi < 4; ++gi) {
            const float4 xa = *(const float4*)&sx[gi][k8*8];
            const float4 xb = *(const float4*)&sx[gi][k8*8 + 4];
            acc[gi] += xa.x*bflo(u.x) + xa.y*bfhi(u.x) + xa.z*bflo(u.y) + xa.w*bfhi(u.y)
                     + xb.x*bflo(u.z) + xb.y*bfhi(u.z) + xb.z*bflo(u.w) + xb.w*bfhi(u.w);
          }
        }
      } else {
        #pragma unroll
        for (int k8 = 0; k8 < 8; ++k8) {
          uint4 u = TW[k8*256 + tt];
          #pragma unroll
          for (int gi = 0; gi < 4; ++gi) {
            const float4 xa = *(const float4*)&sx[gi][k8*8];
            const float4 xb = *(const float4*)&sx[gi][k8*8 + 4];
            acc[gi] += xa.x*bflo(u.x) + xa.y*bfhi(u.x) + xa.z*bflo(u.y) + xa.w*bfhi(u.y)
                     + xb.x*bflo(u.z) + xb.y*bfhi(u.z) + xb.z*bflo(u.w) + xb.w*bfhi(u.w);
          }
        }
      }
      #pragma unroll
      for (int k8 = 0; k8 < 8; ++k8) {
        uint4 u = TU[k8*256 + tt];
        #pragma unroll
        for (int gi = 0; gi < 4; ++gi) {
          const float4 ha = *(const float4*)&shs[gi][l][k8*8];
          const float4 hb = *(const float4*)&shs[gi][l][k8*8 + 4];
          acc[gi] += ha.x*bflo(u.x) + ha.y*bfhi(u.x) + ha.z*bflo(u.y) + ha.w*bfhi(u.y)
                   + hb.x*bflo(u.z) + hb.y*bfhi(u.z) + hb.z*bflo(u.w) + hb.w*bfhi(u.w);
        }
      }
      #pragma unroll
      for (int gi = 0; gi < 4; ++gi) sg[gi][tt] = acc[gi];
      __syncthreads();
      {
        int gq = tt >> 6, r = tt & 63;
        float gv_i = sg[gq][r], gv_f = sg[gq][64+r], gv_g = sg[gq][128+r], gv_o = sg[gq][192+r];
        float c = sigf(gv_f)*scs[gq][l][r] + sigf(gv_i)*tanhf(gv_g);
        float hc = sigf(gv_o)*tanhf(c);
        scs[gq][l][r] = c; shs[gq][l][r] = hc; sx[gq][r] = hc;
      }
      __syncthreads();
    }

    // attention: wave w owns graph g0blk+w; q = sx[w][0:64]
    {
      float q_l = sx[w][lane];
      float lmax = -3.4e38f;
      int i = nstart;
      for (; i + 1 < nend; i += 2) {
        float h0 = h[(size_t)i*64 + lane];
        float h1 = h[(size_t)(i+1)*64 + lane];
        float v0 = h0 * q_l, v1 = h1 * q_l;
        #pragma unroll
        for (int off = 32; off; off >>= 1) { v0 += __shfl_xor(v0, off); v1 += __shfl_xor(v1, off); }
        lmax = fmaxf(lmax, fmaxf(v0, v1));
      }
      if (i < nend) {
        float h0 = h[(size_t)i*64 + lane];
        float v0 = h0 * q_l;
        #pragma unroll
        for (int off = 32; off; off >>= 1) v0 += __shfl_xor(v0, off);
        lmax = fmaxf(lmax, v0);
      }
      float lsum = 0.f, accv = 0.f;
      i = nstart;
      for (; i + 1 < nend; i += 2) {
        float h0 = h[(size_t)i*64 + lane];
        float h1 = h[(size_t)(i+1)*64 + lane];
        float v0 = h0 * q_l, v1 = h1 * q_l;
        #pragma unroll
        for (int off = 32; off; off >>= 1) { v0 += __shfl_xor(v0, off); v1 += __shfl_xor(v1, off); }
        float e0 = expf(v0 - lmax), e1 = expf(v1 - lmax);
        lsum += e0 + e1; accv += e0*h0 + e1*h1;
      }
      if (i < nend) {
        float h0 = h[(size_t)i*64 + lane];
        float v0 = h0 * q_l;
        #pragma unroll
        for (int off = 32; off; off >>= 1) v0 += __shfl_xor(v0, off);
        float e0 = expf(v0 - lmax);
        lsum += e0; accv += e0*h0;
      }
      sq[w][lane] = sx[w][lane];
      sq[w][64 + lane] = accv / fmaxf(lsum, 1e-12f);
    }
    __syncthreads();
  }

  for (int i = tt; i < 512; i += 256) qstar[(size_t)g0blk * 128 + i] = ((float*)sq)[i];
}

// ---------------- head: Linear+ReLU+BN(eval)+Linear + evidential transform; wave per graph
__global__ void head_kernel(const float* qstar, const float* W1, const float* b1,
                            const float* gma, const float* gbe, const float* gme, const float* gva,
                            const float* W2, const float* b2, float* out) {
  __shared__ float hb[4][64];
  int wslot = threadIdx.x >> 6;
  int g = blockIdx.x * 4 + wslot;
  int o = threadIdx.x & 63;
  float acc = b1[o];
  const float* q = qstar + (size_t)g * 128;
  #pragma unroll 4
  for (int k = 0; k < 128; ++k) acc += q[k] * W1[k*64 + o];
  acc = fmaxf(acc, 0.f);
  float hbn = gma[o] * (acc - gme[o]) * rsqrtf(gva[o] + 1e-5f) + gbe[o];
  hb[wslot][o] = hbn;
  __syncthreads();
  if (o < 4) {
    float v = b2[o];
    #pragma unroll 8
    for (int k = 0; k < 64; ++k) v += hb[wslot][k] * W2[k*4 + o];
    float res;
    if (o == 0) res = v;
    else { res = splusf(v) + 1e-6f; if (o == 2) res += 1.f; }
    out[(size_t)g*4 + o] = res;
  }
}

extern "C" void kernel_launch(void* const* d_in, const int* in_sizes, int n_in,
                              void* d_out, int out_size, void* d_ws, size_t ws_size,
                              hipStream_t stream) {
  const float* node_feats = (const float*)d_in[0];
  const float* edge_feats = (const float*)d_in[1];
  const int*   src        = (const int*)d_in[2];
  const int*   dst        = (const int*)d_in[3];
  const int*   n2g        = (const int*)d_in[4];
  const float* W_proj = (const float*)d_in[5];
  const float* b_proj = (const float*)d_in[6];
  const float* W_e1   = (const float*)d_in[7];
  const float* b_e1   = (const float*)d_in[8];
  const float* W_e2   = (const float*)d_in[9];
  const float* b_e2   = (const float*)d_in[10];
  const float* b_conv = (const float*)d_in[11];
  const float* gru_W_ih = (const float*)d_in[12];
  const float* gru_W_hh = (const float*)d_in[13];
  const float* gru_b_ih = (const float*)d_in[14];
  const float* gru_b_hh = (const float*)d_in[15];
  const float* lstm_W_ih0 = (const float*)d_in[16];
  const float* lstm_W_hh0 = (const float*)d_in[17];
  const float* lstm_b_ih0 = (const float*)d_in[18];
  const float* lstm_b_hh0 = (const float*)d_in[19];
  const float* lstm_W_ih_r = (const float*)d_in[20];
  const float* lstm_W_hh_r = (const float*)d_in[21];
  const float* lstm_b_ih_r = (const float*)d_in[22];
  const float* lstm_b_hh_r = (const float*)d_in[23];
  const float* W1 = (const float*)d_in[24];
  const float* b1 = (const float*)d_in[25];
  const float* bn_gamma = (const float*)d_in[26];
  const float* bn_beta  = (const float*)d_in[27];
  const float* bn_mean  = (const float*)d_in[28];
  const float* bn_var   = (const float*)d_in[29];
  const float* W2 = (const float*)d_in[30];
  const float* b2 = (const float*)d_in[31];

  char* ws = (char*)d_ws;
  size_t off = 0;
  auto alloc = [&](size_t n) { size_t c = off; off += (n + 255) & ~(size_t)255; return c; };
  u16*   zb     = (u16*)  (ws + alloc((size_t)MPAD * 128 * 2));   // 12.8 MB
  float* h      = (float*)(ws + alloc((size_t)V_N * 64 * 4));     //  6.4 MB
  float* agg    = (float*)(ws + alloc((size_t)V_N * 64 * 4));     //  6.4 MB
  u16*   WbT    = (u16*)  (ws + alloc((size_t)4096 * 128 * 2));   //  1.0 MB
  float* gWihT  = (float*)(ws + alloc(12288 * 4));
  float* gWhhT  = (float*)(ws + alloc(12288 * 4));
  u32*   TW40   = (u32*)  (ws + alloc(16384 * 4));
  u32*   TU40   = (u32*)  (ws + alloc(8192 * 4));
  u32*   TW4r   = (u32*)  (ws + alloc(16384 * 4));
  u32*   TU4r   = (u32*)  (ws + alloc(16384 * 4));
  int*   gstart = (int*)  (ws + alloc(1025 * 4));
  float* qstar  = (float*)(ws + alloc((size_t)G_N * 128 * 4));
  (void)in_sizes; (void)n_in; (void)out_size; (void)ws_size;

  prep_kernel<<<2368, 256, 0, stream>>>(gru_W_ih, gru_W_hh, lstm_W_ih0, lstm_W_hh0,
                                        lstm_W_ih_r, lstm_W_hh_r, W_e2,
                                        gWihT, gWhhT, TW40, TU40, TW4r, TU4r, WbT);
  proj_kernel<<<6250, 256, 0, stream>>>(node_feats, W_proj, b_proj, h);
  edgenet_kernel<<<MPAD / 2, 256, 0, stream>>>(edge_feats, W_e1, b_e1, zb);
  hipMemsetAsync(agg, 0, (size_t)V_N * 64 * 4, stream);

  for (int st = 0; st < NSTEPS; ++st) {
    fusedmsg_kernel<<<MPAD / 128, 512, 0, stream>>>(zb, WbT, b_e2, h, src, dst, agg);
    gru_kernel<<<1563, 256, 0, stream>>>(agg, b_conv, gWihT, gWhhT, gru_b_ih, gru_b_hh, h, agg);
  }

  gstart_kernel<<<5, 256, 0, stream>>>(n2g, gstart);
  s2s_kernel<<<256, 256, 0, stream>>>(h, gstart, (const uint4*)TW40, (const uint4*)TU40,
                                      (const uint4*)TW4r, (const uint4*)TU4r,
                                      lstm_b_ih0, lstm_b_hh0, lstm_b_ih_r, lstm_b_hh_r, qstar);
  head_kernel<<<256, 256, 0, stream>>>(qstar, W1, b1, bn_gamma, bn_beta, bn_mean, bn_var,
                                       W2, b2, (float*)d_out);
}